// Round 5
// baseline (287.303 us; speedup 1.0000x reference)
//
#include <hip/hip_runtime.h>
#include <hip/hip_bf16.h>

// Problem constants
#define BB 4
#define TT 512
#define TSS 512
#define JJ 17
#define DD 256
#define HH 8
#define MROWS (BB*TT*JJ)            // 34816 = 272 * 128
#define QSCALE 0.2550265247510319f  // 32^-0.5 * log2(e): scores land in log2 domain

typedef short v8s __attribute__((ext_vector_type(8)));   // 8 bf16 in 4 VGPRs
typedef float v4f __attribute__((ext_vector_type(4)));   // MFMA accumulator

// fast f32->bf16, round-half-up (max 0.5 ulp, inputs finite)
__device__ __forceinline__ unsigned short f2bf(float f) {
    union { float f; unsigned int u; } c; c.f = f;
    return (unsigned short)((c.u + 0x8000u) >> 16);
}
// pack two f32 -> (bf16(hi)<<16)|bf16(lo) : 2 adds + 1 v_perm
__device__ __forceinline__ unsigned int pkbf(float lo, float hi) {
    union { float f; unsigned int u; } a, b; a.f = lo; b.f = hi;
    return __builtin_amdgcn_perm(b.u + 0x8000u, a.u + 0x8000u, 0x07060302u);
}
// 8 fp32 (two float4) -> int4 of 8 bf16
__device__ __forceinline__ int4 pk8(float4 x0, float4 x1) {
    int4 r;
    r.x = (int)pkbf(x0.x, x0.y);
    r.y = (int)pkbf(x0.z, x0.w);
    r.z = (int)pkbf(x1.x, x1.y);
    r.w = (int)pkbf(x1.z, x1.w);
    return r;
}

// ---------------------------------------------------------------------------
// GEMM: Y[m][n] = sum_k A[m][k] * W[n][k]   (torch Linear, B^T form)
// 128x128 tile, BK=32, 4 waves (2x2), each wave 4x4 frags of 16x16x32.
// Register double-buffer: tile k+1 prefetched to VGPRs during MFMA on tile k.
// mode 0: A=q (fp32),  W=Wq -> Qp bf16, pre-scaled by QSCALE
// mode 1: A=kv (fp32), W=Wk -> Kp bf16
// mode 2: A=kv (fp32), W=Wv -> Vp bf16
// mode 3: A=Att (bf16),W=Wp -> out fp32 + bias
// ---------------------------------------------------------------------------
__global__ __launch_bounds__(256) void gemm_kernel(
    const float* __restrict__ qf,
    const float* __restrict__ kvf,
    const float* __restrict__ Wqf,
    const float* __restrict__ Wkf,
    const float* __restrict__ Wvf,
    const float* __restrict__ Wpf,
    const float* __restrict__ bpf,
    const unsigned short* __restrict__ att,
    unsigned short* __restrict__ Qp,
    unsigned short* __restrict__ Kp,
    unsigned short* __restrict__ Vp,
    float* __restrict__ outp,
    int mode_base)
{
    const int mode = mode_base + blockIdx.z;
    const float* Af;
    const float* Wf;
    unsigned short* Yp;
    if (mode == 0)      { Af = qf;   Wf = Wqf; Yp = Qp; }
    else if (mode == 1) { Af = kvf;  Wf = Wkf; Yp = Kp; }
    else if (mode == 2) { Af = kvf;  Wf = Wvf; Yp = Vp; }
    else                { Af = 0;    Wf = Wpf; Yp = 0;  }

    const int bm = blockIdx.x;   // 272 M-tiles
    const int bn = blockIdx.y;   // 2 N-tiles

    __shared__ unsigned short As[128 * 40];   // pad 32->40 (conflict-free b128)
    __shared__ unsigned short Bs[128 * 40];

    const int tid  = threadIdx.x;
    const int wave = tid >> 6;
    const int lane = tid & 63;
    const int wm   = wave & 1;
    const int wn   = wave >> 1;
    const int quad = lane >> 4;
    const int l16  = lane & 15;

    // staging slots: thread covers idx = tid and tid+256
    int rowA[2], colA[2];
    #pragma unroll
    for (int c = 0; c < 2; ++c) {
        int idx = c * 256 + tid;
        rowA[c] = idx >> 2;
        colA[c] = (idx & 3) << 3;
    }

    v4f acc[4][4] = {};
    float4 pa0[2], pa1[2], pb0[2], pb1[2];
    int4   pa3[2];

    // preload tile 0
    #pragma unroll
    for (int c = 0; c < 2; ++c) {
        if (mode == 3)
            pa3[c] = *(const int4*)(att + (size_t)(bm * 128 + rowA[c]) * 256 + colA[c]);
        else {
            const float* s = Af + (size_t)(bm * 128 + rowA[c]) * 256 + colA[c];
            pa0[c] = *(const float4*)s; pa1[c] = *(const float4*)(s + 4);
        }
        const float* w = Wf + (size_t)(bn * 128 + rowA[c]) * 256 + colA[c];
        pb0[c] = *(const float4*)w; pb1[c] = *(const float4*)(w + 4);
    }

    for (int kt = 0; kt < 8; ++kt) {
        __syncthreads();   // all waves done reading previous LDS tile
        #pragma unroll
        for (int c = 0; c < 2; ++c) {
            if (mode == 3)
                *(int4*)(&As[rowA[c] * 40 + colA[c]]) = pa3[c];
            else
                *(int4*)(&As[rowA[c] * 40 + colA[c]]) = pk8(pa0[c], pa1[c]);
            *(int4*)(&Bs[rowA[c] * 40 + colA[c]]) = pk8(pb0[c], pb1[c]);
        }
        __syncthreads();

        if (kt < 7) {
            int k0 = (kt + 1) * 32;
            #pragma unroll
            for (int c = 0; c < 2; ++c) {
                if (mode == 3)
                    pa3[c] = *(const int4*)(att + (size_t)(bm * 128 + rowA[c]) * 256 + k0 + colA[c]);
                else {
                    const float* s = Af + (size_t)(bm * 128 + rowA[c]) * 256 + k0 + colA[c];
                    pa0[c] = *(const float4*)s; pa1[c] = *(const float4*)(s + 4);
                }
                const float* w = Wf + (size_t)(bn * 128 + rowA[c]) * 256 + k0 + colA[c];
                pb0[c] = *(const float4*)w; pb1[c] = *(const float4*)(w + 4);
            }
        }

        v8s a[4], b[4];
        #pragma unroll
        for (int i = 0; i < 4; ++i)
            a[i] = *(const v8s*)(&As[(wm * 64 + i * 16 + l16) * 40 + quad * 8]);
        #pragma unroll
        for (int j = 0; j < 4; ++j)
            b[j] = *(const v8s*)(&Bs[(wn * 64 + j * 16 + l16) * 40 + quad * 8]);
        #pragma unroll
        for (int i = 0; i < 4; ++i)
            #pragma unroll
            for (int j = 0; j < 4; ++j)
                acc[i][j] = __builtin_amdgcn_mfma_f32_16x16x32_bf16(
                    a[i], b[j], acc[i][j], 0, 0, 0);
    }

    // epilogue: C/D layout col=lane&15, row=quad*4+reg; row-major stores
    #pragma unroll
    for (int i = 0; i < 4; ++i) {
        #pragma unroll
        for (int j = 0; j < 4; ++j) {
            #pragma unroll
            for (int r = 0; r < 4; ++r) {
                int gm = bm * 128 + wm * 64 + i * 16 + quad * 4 + r;
                int gn = bn * 128 + wn * 64 + j * 16 + l16;
                float v = acc[i][j][r];
                if (mode == 3) {
                    outp[(size_t)gm * 256 + gn] = v + bpf[gn];
                } else {
                    if (mode == 0) v *= QSCALE;
                    Yp[(size_t)gm * 256 + gn] = f2bf(v);
                }
            }
        }
    }
}

// ---------------------------------------------------------------------------
// Fused attention, no-max softmax (scores bounded; Q pre-scaled into log2
// domain). S^T orientation -> packed b64 Ps writes. V transposed into LDS
// with XOR-swizzled s-blocks to kill the cd-group bank pileup.
// ---------------------------------------------------------------------------
#define VST 136   // Vs stride: 272B rows, 16B-aligned b128 reads
#define PST 136   // Ps stride

__global__ __launch_bounds__(256) void attn_kernel(
    const unsigned short* __restrict__ Qp,
    const unsigned short* __restrict__ Kp,
    const unsigned short* __restrict__ Vp,
    unsigned short* __restrict__ Att)
{
    const int bjh = blockIdx.x;   // 0..543
    const int qt  = blockIdx.y;   // 0..3
    const int h   = bjh & 7;
    const int bj  = bjh >> 3;
    const int j   = bj % 17;
    const int b_  = bj / 17;

    __shared__ unsigned short Qs[128 * 40];    // [qrow][cd], pad 40
    __shared__ unsigned short Ks[128 * 40];    // [s][cd],   pad 40
    __shared__ unsigned short Vs[32 * VST];    // [cd][s-chunk], XOR-swizzled
    __shared__ unsigned short Ps[128 * PST];   // [qrow][s-chunk]
    __shared__ float Ls[128];                  // row sums

    const int tid  = threadIdx.x;
    const int wave = tid >> 6;
    const int lane = tid & 63;
    const int quad = lane >> 4;
    const int l16  = lane & 15;

    // stage Q-tile: rows t = qt*128+row, 64B per row
    #pragma unroll
    for (int c = 0; c < 2; ++c) {
        int idx = c * 256 + tid;
        int row = idx >> 2;
        int col = (idx & 3) << 3;
        *(int4*)(&Qs[row * 40 + col]) = *(const int4*)(
            Qp + ((size_t)(b_ * 512 + qt * 128 + row) * 17 + j) * 256 + h * 32 + col);
    }

    float lacc[2] = {0.f, 0.f};
    v4f accO[2][2] = {};

    for (int kc = 0; kc < 4; ++kc) {
        __syncthreads();   // protect previous-iteration Ks/Vs reads
        // stage K chunk [128][32]
        #pragma unroll
        for (int c = 0; c < 2; ++c) {
            int idx = c * 256 + tid;
            int row = idx >> 2;
            int col = (idx & 3) << 3;
            *(int4*)(&Ks[row * 40 + col]) = *(const int4*)(
                Kp + ((size_t)(b_ * 512 + kc * 128 + row) * 17 + j) * 256 + h * 32 + col);
        }
        // stage V chunk transposed with XOR swizzle:
        // element (cd, srow) -> Vs[cd*VST + ((sblk ^ (cd>>3))<<3) + (srow&7)]
        #pragma unroll
        for (int c = 0; c < 2; ++c) {
            int idx  = c * 256 + tid;
            int srow = idx >> 2;
            int cd0  = (idx & 3) << 3;
            int xof  = (((srow >> 3) ^ (cd0 >> 3)) << 3) + (srow & 7);
            union { int4 v; unsigned short s[8]; } u;
            u.v = *(const int4*)(
                Vp + ((size_t)(b_ * 512 + kc * 128 + srow) * 17 + j) * 256 + h * 32 + cd0);
            #pragma unroll
            for (int i = 0; i < 8; ++i)
                Vs[(cd0 + i) * VST + xof] = u.s[i];
        }
        __syncthreads();

        // S^T = K @ Q^T per wave: C-layout col=qrow(l16), row=s=si*16+quad*4+r
        v8s qa[2];
        #pragma unroll
        for (int fi = 0; fi < 2; ++fi)
            qa[fi] = *(const v8s*)(&Qs[(wave * 32 + fi * 16 + l16) * 40 + quad * 8]);
        v4f accST[8][2] = {};
        #pragma unroll
        for (int si = 0; si < 8; ++si) {
            v8s kb = *(const v8s*)(&Ks[(si * 16 + l16) * 40 + quad * 8]);
            #pragma unroll
            for (int fi = 0; fi < 2; ++fi)
                accST[si][fi] = __builtin_amdgcn_mfma_f32_16x16x32_bf16(
                    kb, qa[fi], accST[si][fi], 0, 0, 0);
        }

        // exp2 (no max-sub), perm-packed b64 P writes, lane-local l accum
        #pragma unroll
        for (int fi = 0; fi < 2; ++fi) {
            int prow = (wave * 32 + fi * 16 + l16) * PST;
            #pragma unroll
            for (int si = 0; si < 8; ++si) {
                float p0 = exp2f(accST[si][fi][0]);
                float p1 = exp2f(accST[si][fi][1]);
                float p2 = exp2f(accST[si][fi][2]);
                float p3 = exp2f(accST[si][fi][3]);
                lacc[fi] += (p0 + p1) + (p2 + p3);
                uint2 pk;
                pk.x = pkbf(p0, p1);
                pk.y = pkbf(p2, p3);
                *(uint2*)(&Ps[prow + si * 16 + quad * 4]) = pk;
            }
        }
        // Ps rows are wave-private: drain LDS writes, no block barrier
        asm volatile("s_waitcnt lgkmcnt(0)" ::: "memory");

        // O += P @ V   (P row-major b128; V^T via swizzled rows)
        #pragma unroll
        for (int ks = 0; ks < 4; ++ks) {
            v8s pa[2];
            #pragma unroll
            for (int fi = 0; fi < 2; ++fi)
                pa[fi] = *(const v8s*)(&Ps[(wave * 32 + fi * 16 + l16) * PST +
                                           ks * 32 + quad * 8]);
            #pragma unroll
            for (int nj = 0; nj < 2; ++nj) {
                int cd  = nj * 16 + l16;
                int blk = (ks * 4 + quad) ^ (cd >> 3);
                v8s vb = *(const v8s*)(&Vs[cd * VST + (blk << 3)]);
                #pragma unroll
                for (int fi = 0; fi < 2; ++fi)
                    accO[fi][nj] = __builtin_amdgcn_mfma_f32_16x16x32_bf16(
                        pa[fi], vb, accO[fi][nj], 0, 0, 0);
            }
        }
    }

    // final l: reduce lane partials across the 4 quads sharing each qrow
    #pragma unroll
    for (int fi = 0; fi < 2; ++fi) {
        float lv = lacc[fi];
        lv += __shfl_xor(lv, 16);
        lv += __shfl_xor(lv, 32);
        if (quad == 0) Ls[wave * 32 + fi * 16 + l16] = lv;
    }
    asm volatile("s_waitcnt lgkmcnt(0)" ::: "memory");

    // epilogue: Att row-major [(b,t,j)][(h,cd)]
    #pragma unroll
    for (int fi = 0; fi < 2; ++fi) {
        float4 lv = *(float4*)(&Ls[wave * 32 + fi * 16 + quad * 4]);
        float rl[4] = {1.f / lv.x, 1.f / lv.y, 1.f / lv.z, 1.f / lv.w};
        #pragma unroll
        for (int nj = 0; nj < 2; ++nj) {
            #pragma unroll
            for (int r = 0; r < 4; ++r) {
                int trow = qt * 128 + wave * 32 + fi * 16 + quad * 4 + r;
                int cd   = nj * 16 + l16;
                float v  = accO[fi][nj][r] * rl[r];
                Att[((size_t)(b_ * 512 + trow) * 17 + j) * 256 + h * 32 + cd] = f2bf(v);
            }
        }
    }
}

extern "C" void kernel_launch(void* const* d_in, const int* in_sizes, int n_in,
                              void* d_out, int out_size, void* d_ws, size_t ws_size,
                              hipStream_t stream) {
    const float* q  = (const float*)d_in[0];
    const float* kv = (const float*)d_in[1];
    const float* Wq = (const float*)d_in[2];
    const float* Wk = (const float*)d_in[3];
    const float* Wv = (const float*)d_in[4];
    const float* Wp = (const float*)d_in[5];
    const float* bp = (const float*)d_in[6];

    unsigned short* ws  = (unsigned short*)d_ws;
    const size_t SZ = (size_t)MROWS * DD;      // 8,912,896 elems (~17.8 MB bf16)
    unsigned short* Qp  = ws;
    unsigned short* Kp  = ws + SZ;
    unsigned short* Vp  = ws + 2 * SZ;
    unsigned short* Att = ws + 3 * SZ;
    float* out = (float*)d_out;

    // 1) Q/K/V projections (fp32 in -> bf16 row-major workspace)
    gemm_kernel<<<dim3(272, 2, 3), 256, 0, stream>>>(
        q, kv, Wq, Wk, Wv, Wp, bp, Att, Qp, Kp, Vp, out, 0);
    // 2) fused attention (bf16 in/out, layout adapt in staging)
    attn_kernel<<<dim3(544, 4, 1), 256, 0, stream>>>(Qp, Kp, Vp, Att);
    // 3) output projection + bias (bf16 A, fp32 out)
    gemm_kernel<<<dim3(272, 2, 1), 256, 0, stream>>>(
        q, kv, Wq, Wk, Wv, Wp, bp, Att, Qp, Kp, Vp, out, 3);
}

// Round 6
// 242.847 us; speedup vs baseline: 1.1831x; 1.1831x over previous
//
#include <hip/hip_runtime.h>
#include <hip/hip_bf16.h>

// Problem constants
#define BB 4
#define TT 512
#define JJ 17
#define DD 256
#define HH 8
#define MROWS (BB*TT*JJ)            // 34816 = 272 * 128
#define SZE ((size_t)MROWS * DD)    // 8,912,896 elems
#define WSZ (DD*DD)                 // 65536
#define QSCALE 0.2550265247510319f  // 32^-0.5 * log2(e)

typedef short v8s __attribute__((ext_vector_type(8)));   // 8 bf16 in 4 VGPRs
typedef float v4f __attribute__((ext_vector_type(4)));   // MFMA accumulator

// f32->bf16 round-to-nearest-even (accuracy-critical paths)
__device__ __forceinline__ unsigned short f2bf(float f) {
    union { float f; unsigned int u; } c; c.f = f;
    unsigned int u = c.u;
    return (unsigned short)((u + 0x7FFF + ((u >> 16) & 1)) >> 16);
}
// hot path: pack two f32 -> two bf16 (round-half-up), 2 add + 1 perm
__device__ __forceinline__ unsigned int pkbf(float lo, float hi) {
    union { float f; unsigned int u; } a, b; a.f = lo; b.f = hi;
    return __builtin_amdgcn_perm(b.u + 0x8000u, a.u + 0x8000u, 0x07060302u);
}

// ---------------------------------------------------------------------------
// Prep: fp32 -> bf16 (RNE). q gets QSCALE folded in (linearity of the proj).
// 8 elems/thread, exact grid cover.
// ---------------------------------------------------------------------------
__global__ __launch_bounds__(256) void prep_kernel(
    const float* __restrict__ q, const float* __restrict__ kv,
    const float* __restrict__ Wq, const float* __restrict__ Wk,
    const float* __restrict__ Wv, const float* __restrict__ Wp,
    unsigned short* __restrict__ qb, unsigned short* __restrict__ kvb,
    unsigned short* __restrict__ Wqb, unsigned short* __restrict__ Wkb,
    unsigned short* __restrict__ Wvb, unsigned short* __restrict__ Wpb)
{
    size_t i = ((size_t)blockIdx.x * 256 + threadIdx.x) * 8;
    const float* src; unsigned short* dst; size_t off; float scale = 1.f;
    if (i < SZE)            { src = q;  dst = qb;  off = i;        scale = QSCALE; }
    else if (i < 2 * SZE)   { src = kv; dst = kvb; off = i - SZE; }
    else {
        size_t k = i - 2 * SZE;
        int w = (int)(k >> 16);         // WSZ = 65536
        off = k & (WSZ - 1);
        src = (w == 0) ? Wq : (w == 1) ? Wk : (w == 2) ? Wv : Wp;
        dst = (w == 0) ? Wqb : (w == 1) ? Wkb : (w == 2) ? Wvb : Wpb;
    }
    float4 x0 = *(const float4*)(src + off);
    float4 x1 = *(const float4*)(src + off + 4);
    union { unsigned short s[8]; int4 v; } u;
    u.s[0] = f2bf(x0.x * scale); u.s[1] = f2bf(x0.y * scale);
    u.s[2] = f2bf(x0.z * scale); u.s[3] = f2bf(x0.w * scale);
    u.s[4] = f2bf(x1.x * scale); u.s[5] = f2bf(x1.y * scale);
    u.s[6] = f2bf(x1.z * scale); u.s[7] = f2bf(x1.w * scale);
    *(int4*)(dst + off) = u.v;
}

// ---------------------------------------------------------------------------
// GEMM: Y[m][n] = sum_k A[m][k] * W[n][k], all-bf16 inputs, unified path.
// 128x128 tile, BK=32, 4 waves (2x2), 4x4 frags of 16x16x32.
// Staging writer mapping row=wave*16+l16, colgrp=quad -> 2-way (free) LDS
// bank pattern per 16-lane phase; layout unchanged (pad 40).
// z-selected A/W/Y; fp32out: out = acc + bias (fp32 store).
// ---------------------------------------------------------------------------
__global__ __launch_bounds__(256) void gemm_kernel(
    const unsigned short* __restrict__ A0,
    const unsigned short* __restrict__ A1,
    const unsigned short* __restrict__ A2,
    const unsigned short* __restrict__ W0,
    const unsigned short* __restrict__ W1,
    const unsigned short* __restrict__ W2,
    unsigned short* __restrict__ Y0,
    unsigned short* __restrict__ Y1,
    unsigned short* __restrict__ Y2,
    const float* __restrict__ bias,
    float* __restrict__ outf,
    int fp32out)
{
    const int z = blockIdx.z;
    const unsigned short* A = (z == 0) ? A0 : (z == 1) ? A1 : A2;
    const unsigned short* W = (z == 0) ? W0 : (z == 1) ? W1 : W2;
    unsigned short* Y       = (z == 0) ? Y0 : (z == 1) ? Y1 : Y2;

    const int bm = blockIdx.x;   // 272 M-tiles
    const int bn = blockIdx.y;   // 2 N-tiles

    __shared__ unsigned short As[128 * 40];   // pad 32->40
    __shared__ unsigned short Bs[128 * 40];

    const int tid  = threadIdx.x;
    const int wave = tid >> 6;
    const int lane = tid & 63;
    const int wm   = wave & 1;
    const int wn   = wave >> 1;
    const int quad = lane >> 4;
    const int l16  = lane & 15;

    // staging: lane covers (row = wave*16 + l16 + c*64, colgrp = quad)
    const int colg = quad;
    int srow[2];
    srow[0] = wave * 16 + l16;
    srow[1] = srow[0] + 64;

    v4f acc[4][4] = {};

    for (int kt = 0; kt < 8; ++kt) {
        const int k0 = kt * 32;
        __syncthreads();
        #pragma unroll
        for (int c = 0; c < 2; ++c) {
            *(int4*)(&As[srow[c] * 40 + colg * 8]) =
                *(const int4*)(A + (size_t)(bm * 128 + srow[c]) * 256 + k0 + colg * 8);
            *(int4*)(&Bs[srow[c] * 40 + colg * 8]) =
                *(const int4*)(W + (size_t)(bn * 128 + srow[c]) * 256 + k0 + colg * 8);
        }
        __syncthreads();

        v8s a[4], b[4];
        #pragma unroll
        for (int i = 0; i < 4; ++i)
            a[i] = *(const v8s*)(&As[(wm * 64 + i * 16 + l16) * 40 + quad * 8]);
        #pragma unroll
        for (int j = 0; j < 4; ++j)
            b[j] = *(const v8s*)(&Bs[(wn * 64 + j * 16 + l16) * 40 + quad * 8]);
        #pragma unroll
        for (int i = 0; i < 4; ++i)
            #pragma unroll
            for (int j = 0; j < 4; ++j)
                acc[i][j] = __builtin_amdgcn_mfma_f32_16x16x32_bf16(
                    a[i], b[j], acc[i][j], 0, 0, 0);
    }

    // epilogue: C/D layout col=lane&15, row=quad*4+reg; row-major stores
    #pragma unroll
    for (int i = 0; i < 4; ++i) {
        #pragma unroll
        for (int j = 0; j < 4; ++j) {
            #pragma unroll
            for (int r = 0; r < 4; ++r) {
                int gm = bm * 128 + wm * 64 + i * 16 + quad * 4 + r;
                int gn = bn * 128 + wn * 64 + j * 16 + l16;
                float v = acc[i][j][r];
                if (fp32out)
                    outf[(size_t)gm * 256 + gn] = v + bias[gn];
                else
                    Y[(size_t)gm * 256 + gn] = f2bf(v);
            }
        }
    }
}

// ---------------------------------------------------------------------------
// Fused attention. Q pre-scaled into log2 domain (no-max softmax; scores
// bounded). qa held in registers (no Qs). Per 128-s chunk, ST/softmax/PV
// processed in two 64-s halves so Ps is half-size. LDS = 37.9 KB -> 4
// blocks/CU. Ps rows wave-private -> lgkmcnt-only drains.
// ---------------------------------------------------------------------------
#define VST 136   // Vs stride (16B-aligned rows), XOR-swizzled s-blocks
#define PST 72    // Ps stride: 144B rows, 16B-aligned, 2-way-free

__global__ __launch_bounds__(256) void attn_kernel(
    const unsigned short* __restrict__ Qp,
    const unsigned short* __restrict__ Kp,
    const unsigned short* __restrict__ Vp,
    unsigned short* __restrict__ Att)
{
    const int bjh = blockIdx.x;   // 0..543
    const int qt  = blockIdx.y;   // 0..3
    const int h   = bjh & 7;
    const int bj  = bjh >> 3;
    const int j   = bj % 17;
    const int b_  = bj / 17;

    __shared__ unsigned short Ks[128 * 40];    // [s][cd], pad 40   (10.25 KB)
    __shared__ unsigned short Vs[32 * VST];    // [cd][s], swizzled (8.7 KB)
    __shared__ unsigned short Ps[128 * PST];   // [qrow][s-half]    (18.4 KB)
    __shared__ float Ls[128];                  // row sums          (0.5 KB)

    const int tid  = threadIdx.x;
    const int wave = tid >> 6;
    const int lane = tid & 63;
    const int quad = lane >> 4;
    const int l16  = lane & 15;

    // Q fragments straight from global (each wave reads only its own rows)
    v8s qa[2];
    #pragma unroll
    for (int fi = 0; fi < 2; ++fi)
        qa[fi] = *(const v8s*)(
            Qp + ((size_t)(b_ * 512 + qt * 128 + wave * 32 + fi * 16 + l16) * 17 + j) * 256
               + h * 32 + quad * 8);

    float lacc[2] = {0.f, 0.f};
    v4f accO[2][2] = {};

    for (int kc = 0; kc < 4; ++kc) {
        __syncthreads();   // protect previous-iteration Ks/Vs reads
        // stage K chunk [128][32], conflict-free writer mapping
        #pragma unroll
        for (int c = 0; c < 2; ++c) {
            int krow = wave * 16 + l16 + c * 64;
            *(int4*)(&Ks[krow * 40 + quad * 8]) = *(const int4*)(
                Kp + ((size_t)(b_ * 512 + kc * 128 + krow) * 17 + j) * 256 + h * 32 + quad * 8);
        }
        // stage V chunk transposed with XOR swizzle:
        // (cd, srow) -> Vs[cd*VST + ((sblk ^ (cd>>3))<<3) + (srow&7)]
        #pragma unroll
        for (int c = 0; c < 2; ++c) {
            int idx  = c * 256 + tid;
            int srow = idx >> 2;
            int cd0  = (idx & 3) << 3;
            int xof  = (((srow >> 3) ^ (cd0 >> 3)) << 3) + (srow & 7);
            union { int4 v; unsigned short s[8]; } u;
            u.v = *(const int4*)(
                Vp + ((size_t)(b_ * 512 + kc * 128 + srow) * 17 + j) * 256 + h * 32 + cd0);
            #pragma unroll
            for (int i = 0; i < 8; ++i)
                Vs[(cd0 + i) * VST + xof] = u.s[i];
        }
        __syncthreads();

        #pragma unroll
        for (int half = 0; half < 2; ++half) {
            // S^T = K @ Q^T for this 64-s half; C-layout col=qrow(l16),
            // row = s = (half*4+si)*16 + quad*4 + r
            v4f accST[4][2] = {};
            #pragma unroll
            for (int si = 0; si < 4; ++si) {
                v8s kb = *(const v8s*)(&Ks[((half * 4 + si) * 16 + l16) * 40 + quad * 8]);
                #pragma unroll
                for (int fi = 0; fi < 2; ++fi)
                    accST[si][fi] = __builtin_amdgcn_mfma_f32_16x16x32_bf16(
                        kb, qa[fi], accST[si][fi], 0, 0, 0);
            }
            // exp2 (no max-sub), packed b64 P writes, lane-local l accum
            #pragma unroll
            for (int fi = 0; fi < 2; ++fi) {
                int prow = (wave * 32 + fi * 16 + l16) * PST;
                #pragma unroll
                for (int si = 0; si < 4; ++si) {
                    float p0 = exp2f(accST[si][fi][0]);
                    float p1 = exp2f(accST[si][fi][1]);
                    float p2 = exp2f(accST[si][fi][2]);
                    float p3 = exp2f(accST[si][fi][3]);
                    lacc[fi] += (p0 + p1) + (p2 + p3);
                    uint2 pk;
                    pk.x = pkbf(p0, p1);
                    pk.y = pkbf(p2, p3);
                    *(uint2*)(&Ps[prow + si * 16 + quad * 4]) = pk;
                }
            }
            // Ps rows wave-private: drain LDS writes only
            asm volatile("s_waitcnt lgkmcnt(0)" ::: "memory");

            // O += P @ V over this half (ks local 0..1)
            #pragma unroll
            for (int ks = 0; ks < 2; ++ks) {
                v8s pa[2];
                #pragma unroll
                for (int fi = 0; fi < 2; ++fi)
                    pa[fi] = *(const v8s*)(&Ps[(wave * 32 + fi * 16 + l16) * PST +
                                               ks * 32 + quad * 8]);
                #pragma unroll
                for (int nj = 0; nj < 2; ++nj) {
                    int cd  = nj * 16 + l16;
                    int blk = (half * 8 + ks * 4 + quad) ^ (cd >> 3);
                    v8s vb = *(const v8s*)(&Vs[cd * VST + (blk << 3)]);
                    #pragma unroll
                    for (int fi = 0; fi < 2; ++fi)
                        accO[fi][nj] = __builtin_amdgcn_mfma_f32_16x16x32_bf16(
                            pa[fi], vb, accO[fi][nj], 0, 0, 0);
                }
            }
        }
    }

    // final l: reduce lane partials across the 4 quads sharing each qrow
    #pragma unroll
    for (int fi = 0; fi < 2; ++fi) {
        float lv = lacc[fi];
        lv += __shfl_xor(lv, 16);
        lv += __shfl_xor(lv, 32);
        if (quad == 0) Ls[wave * 32 + fi * 16 + l16] = lv;
    }
    asm volatile("s_waitcnt lgkmcnt(0)" ::: "memory");

    // epilogue: Att row-major [(b,t,j)][(h,cd)]
    #pragma unroll
    for (int fi = 0; fi < 2; ++fi) {
        float4 lv = *(float4*)(&Ls[wave * 32 + fi * 16 + quad * 4]);
        float rl[4] = {1.f / lv.x, 1.f / lv.y, 1.f / lv.z, 1.f / lv.w};
        #pragma unroll
        for (int nj = 0; nj < 2; ++nj) {
            #pragma unroll
            for (int r = 0; r < 4; ++r) {
                int trow = qt * 128 + wave * 32 + fi * 16 + quad * 4 + r;
                int cd   = nj * 16 + l16;
                float v  = accO[fi][nj][r] * rl[r];
                Att[((size_t)(b_ * 512 + trow) * 17 + j) * 256 + h * 32 + cd] = f2bf(v);
            }
        }
    }
}

extern "C" void kernel_launch(void* const* d_in, const int* in_sizes, int n_in,
                              void* d_out, int out_size, void* d_ws, size_t ws_size,
                              hipStream_t stream) {
    const float* q  = (const float*)d_in[0];
    const float* kv = (const float*)d_in[1];
    const float* Wq = (const float*)d_in[2];
    const float* Wk = (const float*)d_in[3];
    const float* Wv = (const float*)d_in[4];
    const float* Wp = (const float*)d_in[5];
    const float* bp = (const float*)d_in[6];

    unsigned short* ws  = (unsigned short*)d_ws;
    unsigned short* Qp  = ws;                 // SZE
    unsigned short* Kp  = ws + SZE;           // SZE
    unsigned short* Vp  = ws + 2 * SZE;       // SZE
    unsigned short* qb  = ws + 3 * SZE;       // SZE (aliased by Att later)
    unsigned short* kvb = ws + 4 * SZE;       // SZE
    unsigned short* Wqb = ws + 5 * SZE;
    unsigned short* Wkb = Wqb + WSZ;
    unsigned short* Wvb = Wkb + WSZ;
    unsigned short* Wpb = Wvb + WSZ;
    unsigned short* Att = qb;                 // qb dead after QKV gemm
    float* out = (float*)d_out;

    // 0) fp32 -> bf16 prep (q scaled by QSCALE); 18,087,936 elems / 2048 = 8832
    prep_kernel<<<8832, 256, 0, stream>>>(q, kv, Wq, Wk, Wv, Wp,
                                          qb, kvb, Wqb, Wkb, Wvb, Wpb);
    // 1) Q/K/V projections (all-bf16)
    gemm_kernel<<<dim3(272, 2, 3), 256, 0, stream>>>(
        qb, kvb, kvb, Wqb, Wkb, Wvb, Qp, Kp, Vp, nullptr, nullptr, 0);
    // 2) fused attention
    attn_kernel<<<dim3(544, 4, 1), 256, 0, stream>>>(Qp, Kp, Vp, Att);
    // 3) output projection + bias (fp32 out)
    gemm_kernel<<<dim3(272, 2, 1), 256, 0, stream>>>(
        Att, Att, Att, Wpb, Wpb, Wpb, nullptr, nullptr, nullptr, bp, out, 1);
}